// Round 1
// baseline (423.771 us; speedup 1.0000x reference)
//
#include <hip/hip_runtime.h>
#include <hip/hip_bf16.h>
#include <math.h>

constexpr int F  = 256;
constexpr int ED = 32;
constexpr int H  = 128;

// ---------------- Kernel A: fused projections ----------------
// ps = x @ we_src [N,32], pd = x @ we_dst [N,32], h = relu(x @ wc + bc) [N,128]
// 4 nodes per block of 192 threads; x rows staged in LDS; weight reads are
// coalesced (consecutive lanes -> consecutive columns) and L2-resident.
__global__ __launch_bounds__(192) void proj_kernel(
    const float* __restrict__ x, const float* __restrict__ we_src,
    const float* __restrict__ we_dst, const float* __restrict__ wc,
    const float* __restrict__ bc,
    float* __restrict__ ps, float* __restrict__ pd, float* __restrict__ h,
    int N)
{
    __shared__ float xs[4][F];
    const int n0 = blockIdx.x * 4;
    const int t  = threadIdx.x;

    for (int idx = t; idx < 4 * F; idx += 192) {
        int r = idx >> 8, k = idx & (F - 1);
        int n = n0 + r;
        xs[r][k] = (n < N) ? x[(size_t)n * F + k] : 0.0f;
    }
    __syncthreads();

    float a0 = 0.f, a1 = 0.f, a2 = 0.f, a3 = 0.f;
    if (t < 64) {
        const float* W = (t < 32) ? we_src : we_dst;
        const int j = t & 31;
        #pragma unroll 4
        for (int k = 0; k < F; ++k) {
            float w = W[k * ED + j];
            a0 += xs[0][k] * w;
            a1 += xs[1][k] * w;
            a2 += xs[2][k] * w;
            a3 += xs[3][k] * w;
        }
        float* out = (t < 32) ? ps : pd;
        if (n0 + 0 < N) out[(size_t)(n0 + 0) * ED + j] = a0;
        if (n0 + 1 < N) out[(size_t)(n0 + 1) * ED + j] = a1;
        if (n0 + 2 < N) out[(size_t)(n0 + 2) * ED + j] = a2;
        if (n0 + 3 < N) out[(size_t)(n0 + 3) * ED + j] = a3;
    } else {
        const int j = t - 64;   // 0..127
        #pragma unroll 4
        for (int k = 0; k < F; ++k) {
            float w = wc[k * H + j];
            a0 += xs[0][k] * w;
            a1 += xs[1][k] * w;
            a2 += xs[2][k] * w;
            a3 += xs[3][k] * w;
        }
        float b = bc[j];
        if (n0 + 0 < N) h[(size_t)(n0 + 0) * H + j] = fmaxf(a0 + b, 0.f);
        if (n0 + 1 < N) h[(size_t)(n0 + 1) * H + j] = fmaxf(a1 + b, 0.f);
        if (n0 + 2 < N) h[(size_t)(n0 + 2) * H + j] = fmaxf(a2 + b, 0.f);
        if (n0 + 3 < N) h[(size_t)(n0 + 3) * H + j] = fmaxf(a3 + b, 0.f);
    }
}

// ---------------- Kernel B: edge gate + deg ----------------
__global__ __launch_bounds__(256) void edge_gate_kernel(
    const int* __restrict__ ei, const float* __restrict__ ps,
    const float* __restrict__ pd, const float* __restrict__ be,
    const float* __restrict__ we2, const float* __restrict__ be2,
    float* __restrict__ gate, float* __restrict__ deg, int E)
{
    __shared__ float sbe[ED], swe2[ED];
    const int t = threadIdx.x;
    if (t < ED) { sbe[t] = be[t]; swe2[t] = we2[t]; }
    __syncthreads();

    const int e = blockIdx.x * 256 + t;
    if (e >= E) return;
    const int s = ei[e];
    const int d = ei[E + e];

    const float4* p4 = (const float4*)(ps + (size_t)s * ED);
    const float4* q4 = (const float4*)(pd + (size_t)d * ED);
    float acc = 0.f;
    #pragma unroll
    for (int j4 = 0; j4 < ED / 4; ++j4) {
        float4 a = p4[j4];
        float4 b = q4[j4];
        int j = j4 * 4;
        acc += fmaxf(a.x + b.x + sbe[j + 0], 0.f) * swe2[j + 0];
        acc += fmaxf(a.y + b.y + sbe[j + 1], 0.f) * swe2[j + 1];
        acc += fmaxf(a.z + b.z + sbe[j + 2], 0.f) * swe2[j + 2];
        acc += fmaxf(a.w + b.w + sbe[j + 3], 0.f) * swe2[j + 3];
    }
    float logit = acc + be2[0];
    float sg = 1.0f / (1.0f + expf(-logit));
    float gt = sg * 1.2f - 0.1f;          // s*(ZETA-GAMMA)+GAMMA
    gt = fminf(fmaxf(gt, 0.0f), 1.0f);
    gate[e] = gt;
    if (gt > 0.0f) atomicAdd(&deg[d], gt);
}

// ---------------- Kernel C: softmax stats over deg (single block) ----------------
__global__ __launch_bounds__(1024) void deg_stats_kernel(
    const float* __restrict__ deg, float* __restrict__ mS, int N)
{
    __shared__ float red[1024];
    const int t = threadIdx.x;
    float m = -1e30f;
    for (int i = t; i < N; i += 1024) m = fmaxf(m, deg[i]);
    red[t] = m; __syncthreads();
    for (int s = 512; s > 0; s >>= 1) {
        if (t < s) red[t] = fmaxf(red[t], red[t + s]);
        __syncthreads();
    }
    const float mx = red[0];
    __syncthreads();
    float sum = 0.f;
    for (int i = t; i < N; i += 1024) sum += expf(deg[i] - mx);
    red[t] = sum; __syncthreads();
    for (int s = 512; s > 0; s >>= 1) {
        if (t < s) red[t] += red[t + s];
        __syncthreads();
    }
    if (t == 0) { mS[0] = mx; mS[1] = red[0]; }
}

// ---------------- Kernel D: att + c elementwise ----------------
__global__ __launch_bounds__(256) void attc_kernel(
    const float* __restrict__ deg, const float* __restrict__ mS,
    float* __restrict__ att, float* __restrict__ c, int N)
{
    const int i = blockIdx.x * 256 + threadIdx.x;
    if (i >= N) return;
    float a = expf(deg[i] - mS[0]) / mS[1];
    att[i] = a;
    c[i] = a / (deg[i] + 1e-6f);
}

// ---------------- Kernel E: u[src] += gate*c[dst] ----------------
__global__ __launch_bounds__(256) void edge_u_kernel(
    const int* __restrict__ ei, const float* __restrict__ gate,
    const float* __restrict__ c, float* __restrict__ u, int E)
{
    const int e = blockIdx.x * 256 + threadIdx.x;
    if (e >= E) return;
    float gt = gate[e];
    if (gt != 0.f) {
        int s = ei[e];
        int d = ei[E + e];
        atomicAdd(&u[s], gt * c[d]);
    }
}

// ---------------- Kernel F: g = sum_i (att[i]+u[i]) * h[i,:] ----------------
__global__ __launch_bounds__(128) void pool_kernel(
    const float* __restrict__ h, const float* __restrict__ att,
    const float* __restrict__ u, float* __restrict__ gacc, int N)
{
    const int t = threadIdx.x;
    float acc = 0.f;
    for (int n = blockIdx.x; n < N; n += gridDim.x) {
        float w = att[n] + u[n];
        acc += w * h[(size_t)n * H + t];
    }
    atomicAdd(&gacc[t], acc);
}

// ---------------- Kernel G: classifier (1 wave) ----------------
__global__ __launch_bounds__(64) void cls_kernel(
    const float* __restrict__ gacc, const float* __restrict__ w1,
    const float* __restrict__ b1, const float* __restrict__ ln_g,
    const float* __restrict__ ln_b, const float* __restrict__ w2,
    const float* __restrict__ b2, float* __restrict__ out)
{
    __shared__ float gs[H];
    const int t = threadIdx.x;   // 0..63
    gs[t] = gacc[t];
    gs[t + 64] = gacc[t + 64];
    __syncthreads();

    float acc = b1[t];
    #pragma unroll 4
    for (int k = 0; k < H; ++k) acc += gs[k] * w1[k * 64 + t];
    float z = fmaxf(acc, 0.f);

    // mean
    float sm = z;
    #pragma unroll
    for (int m = 1; m < 64; m <<= 1) sm += __shfl_xor(sm, m);
    float mn = sm * (1.0f / 64.0f);
    // var (biased)
    float dv = (z - mn) * (z - mn);
    float sv = dv;
    #pragma unroll
    for (int m = 1; m < 64; m <<= 1) sv += __shfl_xor(sv, m);
    float var = sv * (1.0f / 64.0f);

    float zn = (z - mn) * rsqrtf(var + 1e-5f) * ln_g[t] + ln_b[t];

    // spectral norm of w2 [64,2] via 2x2 Gram eigenvalue
    float w20 = w2[t * 2 + 0];
    float w21 = w2[t * 2 + 1];
    float ga = w20 * w20, gb = w20 * w21, gc = w21 * w21;
    float p0 = zn * w20, p1 = zn * w21;
    #pragma unroll
    for (int m = 1; m < 64; m <<= 1) {
        ga += __shfl_xor(ga, m);
        gb += __shfl_xor(gb, m);
        gc += __shfl_xor(gc, m);
        p0 += __shfl_xor(p0, m);
        p1 += __shfl_xor(p1, m);
    }
    if (t == 0) {
        float tr = ga + gc;
        float df = ga - gc;
        float eig = 0.5f * (tr + sqrtf(df * df + 4.0f * gb * gb));
        float sigma = sqrtf(eig);
        out[0] = p0 / sigma + b2[0];
        out[1] = p1 / sigma + b2[1];
    }
}

extern "C" void kernel_launch(void* const* d_in, const int* in_sizes, int n_in,
                              void* d_out, int out_size, void* d_ws, size_t ws_size,
                              hipStream_t stream) {
    const float* x      = (const float*)d_in[0];
    const int*   ei     = (const int*)  d_in[1];
    const float* we_src = (const float*)d_in[2];
    const float* we_dst = (const float*)d_in[3];
    const float* be     = (const float*)d_in[4];
    const float* we2    = (const float*)d_in[5];
    const float* be2    = (const float*)d_in[6];
    const float* wc     = (const float*)d_in[7];
    const float* bc     = (const float*)d_in[8];
    const float* w1     = (const float*)d_in[9];
    const float* b1     = (const float*)d_in[10];
    const float* ln_g   = (const float*)d_in[11];
    const float* ln_b   = (const float*)d_in[12];
    const float* w2     = (const float*)d_in[13];
    const float* b2     = (const float*)d_in[14];

    const int N = in_sizes[0] / F;
    const int E = in_sizes[1] / 2;

    float* ws = (float*)d_ws;
    size_t off = 0;
    float* deg  = ws + off; off += (size_t)N;
    float* u    = ws + off; off += (size_t)N;
    float* gacc = ws + off; off += 128;
    const size_t zcount = off;            // deg, u, gacc zeroed together
    float* att  = ws + off; off += (size_t)N;
    float* c    = ws + off; off += (size_t)N;
    float* mS   = ws + off; off += 2;
    off = (off + 15) & ~(size_t)15;       // 16-float align for float4 loads
    float* ps   = ws + off; off += (size_t)N * ED;
    float* pdp  = ws + off; off += (size_t)N * ED;
    float* h    = ws + off; off += (size_t)N * H;
    float* gate = ws + off; off += (size_t)E;

    hipMemsetAsync(deg, 0, zcount * sizeof(float), stream);

    proj_kernel<<<(N + 3) / 4, 192, 0, stream>>>(x, we_src, we_dst, wc, bc, ps, pdp, h, N);
    edge_gate_kernel<<<(E + 255) / 256, 256, 0, stream>>>(ei, ps, pdp, be, we2, be2, gate, deg, E);
    deg_stats_kernel<<<1, 1024, 0, stream>>>(deg, mS, N);
    attc_kernel<<<(N + 255) / 256, 256, 0, stream>>>(deg, mS, att, c, N);
    edge_u_kernel<<<(E + 255) / 256, 256, 0, stream>>>(ei, gate, c, u, E);
    pool_kernel<<<256, 128, 0, stream>>>(h, att, u, gacc, N);
    cls_kernel<<<1, 64, 0, stream>>>(gacc, w1, b1, ln_g, ln_b, w2, b2, (float*)d_out);
}

// Round 2
// 309.965 us; speedup vs baseline: 1.3672x; 1.3672x over previous
//
#include <hip/hip_runtime.h>
#include <hip/hip_bf16.h>
#include <math.h>

constexpr int F  = 256;
constexpr int ED = 32;
constexpr int H  = 128;
constexpr int NC = 192;          // concat output cols: 32 ps | 32 pd | 128 h

typedef __attribute__((ext_vector_type(8))) short  short8v;
typedef __attribute__((ext_vector_type(4))) float  float4v;

static __device__ __forceinline__ unsigned short f2bf(float f) {
    unsigned int u = __float_as_uint(f);
    unsigned int r = (u + 0x7FFFu + ((u >> 16) & 1u)) >> 16;   // RNE
    return (unsigned short)r;
}

// ---------------- Kernel P0: pack weights into MFMA B-fragment order ----------------
// Wp[tile][ks][lane][j] (bf16), tile=0..11 (16-col tiles over 192), ks=0..7 (K steps of 32),
// element = Wcat[k = ks*32 + (lane>>4)*8 + j][col = tile*16 + (lane&15)]
__global__ __launch_bounds__(256) void pack_kernel(
    const float* __restrict__ we_src, const float* __restrict__ we_dst,
    const float* __restrict__ wc, unsigned short* __restrict__ Wp)
{
    int id = blockIdx.x * 256 + threadIdx.x;      // 0 .. 12*8*64-1
    if (id >= 12 * 8 * 64) return;
    int lane = id & 63;
    int ks   = (id >> 6) & 7;
    int tile = id >> 9;
    int col  = tile * 16 + (lane & 15);
    int kb   = ks * 32 + (lane >> 4) * 8;

    short8v v;
    #pragma unroll
    for (int j = 0; j < 8; ++j) {
        int k = kb + j;
        float w;
        if (col < 32)       w = we_src[k * ED + col];
        else if (col < 64)  w = we_dst[k * ED + (col - 32)];
        else                w = wc[k * H + (col - 64)];
        v[j] = (short)f2bf(w);
    }
    *(short8v*)(Wp + (size_t)id * 8) = v;
}

// ---------------- Kernel P1: MFMA GEMM  C[N,192] = bf16(x) @ Wcat, relu+bc on cols>=64 ----
// Block: 256 thr (4 waves). Wave w owns cols [48w, 48w+48) = 3 col-tiles; B held in VGPRs.
// A: 16-row tile staged f32->bf16 into XOR-swizzled LDS (reg-staged, both-sides swizzle).
__global__ __launch_bounds__(256) void gemm_kernel(
    const float* __restrict__ x, const unsigned short* __restrict__ Wp,
    const float* __restrict__ bc, float* __restrict__ C, int M16)
{
    __shared__ __align__(16) unsigned char As[16 * 512];   // 16 rows x 256 bf16

    const int t    = threadIdx.x;
    const int w    = t >> 6;
    const int lane = t & 63;

    // --- B preload: 3 col-tiles x 8 k-steps, fragment order, coalesced ---
    const short8v* WpV = (const short8v*)Wp;
    short8v Bfr[3][8];
    #pragma unroll
    for (int ct = 0; ct < 3; ++ct)
        #pragma unroll
        for (int ks = 0; ks < 8; ++ks)
            Bfr[ct][ks] = WpV[(((w * 3 + ct) * 8 + ks) << 6) + lane];

    const int srow = t >> 4;          // staging: row 0..15
    const int sseg = t & 15;          // 16-float segment
    const int ssw  = (srow & 7) << 4;

    const int arow = lane & 15;       // A-frag row
    const int asw  = (arow & 7) << 4;
    const int akb  = (lane >> 4) * 16;   // byte offset of 8-bf16 group within k-step

    const int crow0 = (lane >> 4) * 4;
    const int ccol  = lane & 15;

    for (int rt = blockIdx.x; rt < M16; rt += gridDim.x) {
        const int n0 = rt * 16;

        // --- stage: load 16 f32, convert, 2x ds_write_b128 (swizzled) ---
        {
            const float4* src = (const float4*)(x + (size_t)(n0 + srow) * F + sseg * 16);
            float4 f0 = src[0], f1 = src[1], f2 = src[2], f3 = src[3];
            short8v lo, hi;
            lo[0] = (short)f2bf(f0.x); lo[1] = (short)f2bf(f0.y);
            lo[2] = (short)f2bf(f0.z); lo[3] = (short)f2bf(f0.w);
            lo[4] = (short)f2bf(f1.x); lo[5] = (short)f2bf(f1.y);
            lo[6] = (short)f2bf(f1.z); lo[7] = (short)f2bf(f1.w);
            hi[0] = (short)f2bf(f2.x); hi[1] = (short)f2bf(f2.y);
            hi[2] = (short)f2bf(f2.z); hi[3] = (short)f2bf(f2.w);
            hi[4] = (short)f2bf(f3.x); hi[5] = (short)f2bf(f3.y);
            hi[6] = (short)f2bf(f3.z); hi[7] = (short)f2bf(f3.w);
            int base = srow * 512 + sseg * 32;
            *(short8v*)&As[srow * 512 + ((sseg * 32 +  0) ^ ssw)] = lo;
            *(short8v*)&As[srow * 512 + ((sseg * 32 + 16) ^ ssw)] = hi;
            (void)base;
        }
        __syncthreads();

        // --- compute: 8 k-steps, 1 A-read + 3 MFMA each ---
        float4v accs[3];
        #pragma unroll
        for (int ct = 0; ct < 3; ++ct) accs[ct] = (float4v){0.f, 0.f, 0.f, 0.f};

        #pragma unroll
        for (int ks = 0; ks < 8; ++ks) {
            short8v a = *(const short8v*)&As[arow * 512 + ((ks * 64 + akb) ^ asw)];
            accs[0] = __builtin_amdgcn_mfma_f32_16x16x32_bf16(a, Bfr[0][ks], accs[0], 0, 0, 0);
            accs[1] = __builtin_amdgcn_mfma_f32_16x16x32_bf16(a, Bfr[1][ks], accs[1], 0, 0, 0);
            accs[2] = __builtin_amdgcn_mfma_f32_16x16x32_bf16(a, Bfr[2][ks], accs[2], 0, 0, 0);
        }

        // --- epilogue: C/D layout col=lane&15, row=(lane>>4)*4+r ---
        #pragma unroll
        for (int ct = 0; ct < 3; ++ct) {
            int gcol = w * 48 + ct * 16 + ccol;
            float bias = (gcol >= 64) ? bc[gcol - 64] : 0.0f;
            #pragma unroll
            for (int r = 0; r < 4; ++r) {
                float v = accs[ct][r];
                if (gcol >= 64) v = fmaxf(v + bias, 0.0f);
                C[(size_t)(n0 + crow0 + r) * NC + gcol] = v;
            }
        }
        __syncthreads();
    }
}

// ---------------- Kernel B: edge gate + deg ----------------
__global__ __launch_bounds__(256) void edge_gate_kernel(
    const int* __restrict__ ei, const float* __restrict__ C,
    const float* __restrict__ be, const float* __restrict__ we2,
    const float* __restrict__ be2,
    float* __restrict__ gate, float* __restrict__ deg, int E)
{
    __shared__ float sbe[ED], swe2[ED];
    const int t = threadIdx.x;
    if (t < ED) { sbe[t] = be[t]; swe2[t] = we2[t]; }
    __syncthreads();

    const int e = blockIdx.x * 256 + t;
    if (e >= E) return;
    const int s = ei[e];
    const int d = ei[E + e];

    const float4* p4 = (const float4*)(C + (size_t)s * NC);        // ps at col 0
    const float4* q4 = (const float4*)(C + (size_t)d * NC + 32);   // pd at col 32
    float acc = 0.f;
    #pragma unroll
    for (int j4 = 0; j4 < ED / 4; ++j4) {
        float4 a = p4[j4];
        float4 b = q4[j4];
        int j = j4 * 4;
        acc += fmaxf(a.x + b.x + sbe[j + 0], 0.f) * swe2[j + 0];
        acc += fmaxf(a.y + b.y + sbe[j + 1], 0.f) * swe2[j + 1];
        acc += fmaxf(a.z + b.z + sbe[j + 2], 0.f) * swe2[j + 2];
        acc += fmaxf(a.w + b.w + sbe[j + 3], 0.f) * swe2[j + 3];
    }
    float logit = acc + be2[0];
    float sg = 1.0f / (1.0f + expf(-logit));
    float gt = sg * 1.2f - 0.1f;
    gt = fminf(fmaxf(gt, 0.0f), 1.0f);
    gate[e] = gt;
    if (gt > 0.0f) atomicAdd(&deg[d], gt);
}

// ---------------- Kernel C: softmax stats over deg (single block) ----------------
__global__ __launch_bounds__(1024) void deg_stats_kernel(
    const float* __restrict__ deg, float* __restrict__ mS, int N)
{
    __shared__ float red[1024];
    const int t = threadIdx.x;
    float m = -1e30f;
    for (int i = t; i < N; i += 1024) m = fmaxf(m, deg[i]);
    red[t] = m; __syncthreads();
    for (int s = 512; s > 0; s >>= 1) {
        if (t < s) red[t] = fmaxf(red[t], red[t + s]);
        __syncthreads();
    }
    const float mx = red[0];
    __syncthreads();
    float sum = 0.f;
    for (int i = t; i < N; i += 1024) sum += expf(deg[i] - mx);
    red[t] = sum; __syncthreads();
    for (int s = 512; s > 0; s >>= 1) {
        if (t < s) red[t] += red[t + s];
        __syncthreads();
    }
    if (t == 0) { mS[0] = mx; mS[1] = red[0]; }
}

// ---------------- Kernel D: att + c elementwise ----------------
__global__ __launch_bounds__(256) void attc_kernel(
    const float* __restrict__ deg, const float* __restrict__ mS,
    float* __restrict__ att, float* __restrict__ c, int N)
{
    const int i = blockIdx.x * 256 + threadIdx.x;
    if (i >= N) return;
    float a = expf(deg[i] - mS[0]) / mS[1];
    att[i] = a;
    c[i] = a / (deg[i] + 1e-6f);
}

// ---------------- Kernel E: u[src] += gate*c[dst] ----------------
__global__ __launch_bounds__(256) void edge_u_kernel(
    const int* __restrict__ ei, const float* __restrict__ gate,
    const float* __restrict__ c, float* __restrict__ u, int E)
{
    const int e = blockIdx.x * 256 + threadIdx.x;
    if (e >= E) return;
    float gt = gate[e];
    if (gt != 0.f) {
        int s = ei[e];
        int d = ei[E + e];
        atomicAdd(&u[s], gt * c[d]);
    }
}

// ---------------- Kernel F: g = sum_i (att[i]+u[i]) * h[i,:] (h = C cols 64..191) ----
__global__ __launch_bounds__(128) void pool_kernel(
    const float* __restrict__ C, const float* __restrict__ att,
    const float* __restrict__ u, float* __restrict__ gacc, int N)
{
    const int t = threadIdx.x;
    float acc = 0.f;
    for (int n = blockIdx.x; n < N; n += gridDim.x) {
        float wgt = att[n] + u[n];
        acc += wgt * C[(size_t)n * NC + 64 + t];
    }
    atomicAdd(&gacc[t], acc);
}

// ---------------- Kernel G: classifier (1 wave) ----------------
__global__ __launch_bounds__(64) void cls_kernel(
    const float* __restrict__ gacc, const float* __restrict__ w1,
    const float* __restrict__ b1, const float* __restrict__ ln_g,
    const float* __restrict__ ln_b, const float* __restrict__ w2,
    const float* __restrict__ b2, float* __restrict__ out)
{
    __shared__ float gs[H];
    const int t = threadIdx.x;   // 0..63
    gs[t] = gacc[t];
    gs[t + 64] = gacc[t + 64];
    __syncthreads();

    float acc = b1[t];
    #pragma unroll 4
    for (int k = 0; k < H; ++k) acc += gs[k] * w1[k * 64 + t];
    float z = fmaxf(acc, 0.f);

    float sm = z;
    #pragma unroll
    for (int m = 1; m < 64; m <<= 1) sm += __shfl_xor(sm, m);
    float mn = sm * (1.0f / 64.0f);
    float dv = (z - mn) * (z - mn);
    float sv = dv;
    #pragma unroll
    for (int m = 1; m < 64; m <<= 1) sv += __shfl_xor(sv, m);
    float var = sv * (1.0f / 64.0f);

    float zn = (z - mn) * rsqrtf(var + 1e-5f) * ln_g[t] + ln_b[t];

    float w20 = w2[t * 2 + 0];
    float w21 = w2[t * 2 + 1];
    float ga = w20 * w20, gb = w20 * w21, gc = w21 * w21;
    float p0 = zn * w20, p1 = zn * w21;
    #pragma unroll
    for (int m = 1; m < 64; m <<= 1) {
        ga += __shfl_xor(ga, m);
        gb += __shfl_xor(gb, m);
        gc += __shfl_xor(gc, m);
        p0 += __shfl_xor(p0, m);
        p1 += __shfl_xor(p1, m);
    }
    if (t == 0) {
        float tr = ga + gc;
        float df = ga - gc;
        float eig = 0.5f * (tr + sqrtf(df * df + 4.0f * gb * gb));
        float sigma = sqrtf(eig);
        out[0] = p0 / sigma + b2[0];
        out[1] = p1 / sigma + b2[1];
    }
}

extern "C" void kernel_launch(void* const* d_in, const int* in_sizes, int n_in,
                              void* d_out, int out_size, void* d_ws, size_t ws_size,
                              hipStream_t stream) {
    const float* x      = (const float*)d_in[0];
    const int*   ei     = (const int*)  d_in[1];
    const float* we_src = (const float*)d_in[2];
    const float* we_dst = (const float*)d_in[3];
    const float* be     = (const float*)d_in[4];
    const float* we2    = (const float*)d_in[5];
    const float* be2    = (const float*)d_in[6];
    const float* wc     = (const float*)d_in[7];
    const float* bc     = (const float*)d_in[8];
    const float* w1     = (const float*)d_in[9];
    const float* b1     = (const float*)d_in[10];
    const float* ln_g   = (const float*)d_in[11];
    const float* ln_b   = (const float*)d_in[12];
    const float* w2     = (const float*)d_in[13];
    const float* b2     = (const float*)d_in[14];

    const int N = in_sizes[0] / F;
    const int E = in_sizes[1] / 2;
    const int M16 = N / 16;                // 3125 exact for N=50000

    float* ws = (float*)d_ws;
    size_t off = 0;
    float* deg  = ws + off; off += (size_t)N;
    float* u    = ws + off; off += (size_t)N;
    float* gacc = ws + off; off += 128;
    const size_t zcount = off;             // deg, u, gacc zeroed together
    float* att  = ws + off; off += (size_t)N;
    float* c    = ws + off; off += (size_t)N;
    float* mS   = ws + off; off += 2;
    off = (off + 15) & ~(size_t)15;
    unsigned short* Wp = (unsigned short*)(ws + off); off += (12 * 8 * 64 * 8) / 2;
    float* C    = ws + off; off += (size_t)N * NC;
    float* gate = ws + off; off += (size_t)E;

    hipMemsetAsync(deg, 0, zcount * sizeof(float), stream);

    pack_kernel<<<(12 * 8 * 64 + 255) / 256, 256, 0, stream>>>(we_src, we_dst, wc, Wp);
    gemm_kernel<<<1024, 256, 0, stream>>>(x, Wp, bc, C, M16);
    edge_gate_kernel<<<(E + 255) / 256, 256, 0, stream>>>(ei, C, be, we2, be2, gate, deg, E);
    deg_stats_kernel<<<1, 1024, 0, stream>>>(deg, mS, N);
    attc_kernel<<<(N + 255) / 256, 256, 0, stream>>>(deg, mS, att, c, N);
    edge_u_kernel<<<(E + 255) / 256, 256, 0, stream>>>(ei, gate, c, u, E);
    pool_kernel<<<512, 128, 0, stream>>>(C, att, u, gacc, N);
    cls_kernel<<<1, 64, 0, stream>>>(gacc, w1, b1, ln_g, ln_b, w2, b2, (float*)d_out);
}

// Round 3
// 292.259 us; speedup vs baseline: 1.4500x; 1.0606x over previous
//
#include <hip/hip_runtime.h>
#include <hip/hip_bf16.h>
#include <math.h>

constexpr int F  = 256;
constexpr int ED = 32;
constexpr int H  = 128;

typedef __attribute__((ext_vector_type(8))) short    short8v;
typedef __attribute__((ext_vector_type(4))) float    float4v;
typedef __attribute__((ext_vector_type(8))) _Float16 half8v;

static __device__ __forceinline__ unsigned short f2bf(float f) {
    unsigned int u = __float_as_uint(f);
    unsigned int r = (u + 0x7FFFu + ((u >> 16) & 1u)) >> 16;   // RNE
    return (unsigned short)r;
}

// ---------------- Kernel P0: pack weights into MFMA B-fragment order ----------------
__global__ __launch_bounds__(256) void pack_kernel(
    const float* __restrict__ we_src, const float* __restrict__ we_dst,
    const float* __restrict__ wc, unsigned short* __restrict__ Wp)
{
    int id = blockIdx.x * 256 + threadIdx.x;      // 0 .. 12*8*64-1
    if (id >= 12 * 8 * 64) return;
    int lane = id & 63;
    int ks   = (id >> 6) & 7;
    int tile = id >> 9;
    int col  = tile * 16 + (lane & 15);
    int kb   = ks * 32 + (lane >> 4) * 8;

    short8v v;
    #pragma unroll
    for (int j = 0; j < 8; ++j) {
        int k = kb + j;
        float w;
        if (col < 32)       w = we_src[k * ED + col];
        else if (col < 64)  w = we_dst[k * ED + (col - 32)];
        else                w = wc[k * H + (col - 64)];
        v[j] = (short)f2bf(w);
    }
    *(short8v*)(Wp + (size_t)id * 8) = v;
}

// ---------------- Kernel P1: MFMA GEMM -> psh/pdh/hh (all f16) ----------------
__global__ __launch_bounds__(256) void gemm_kernel(
    const float* __restrict__ x, const unsigned short* __restrict__ Wp,
    const float* __restrict__ bc,
    _Float16* __restrict__ psh, _Float16* __restrict__ pdh,
    _Float16* __restrict__ hh, int M16)
{
    __shared__ __align__(16) unsigned char As[16 * 512];   // 16 rows x 256 bf16

    const int t    = threadIdx.x;
    const int w    = t >> 6;
    const int lane = t & 63;

    const short8v* WpV = (const short8v*)Wp;
    short8v Bfr[3][8];
    #pragma unroll
    for (int ct = 0; ct < 3; ++ct)
        #pragma unroll
        for (int ks = 0; ks < 8; ++ks)
            Bfr[ct][ks] = WpV[(((w * 3 + ct) * 8 + ks) << 6) + lane];

    const int srow = t >> 4;
    const int sseg = t & 15;
    const int ssw  = (srow & 7) << 4;

    const int arow = lane & 15;
    const int asw  = (arow & 7) << 4;
    const int akb  = (lane >> 4) * 16;

    const int crow0 = (lane >> 4) * 4;
    const int ccol  = lane & 15;

    for (int rt = blockIdx.x; rt < M16; rt += gridDim.x) {
        const int n0 = rt * 16;

        {
            const float4* src = (const float4*)(x + (size_t)(n0 + srow) * F + sseg * 16);
            float4 f0 = src[0], f1 = src[1], f2 = src[2], f3 = src[3];
            short8v lo, hi;
            lo[0] = (short)f2bf(f0.x); lo[1] = (short)f2bf(f0.y);
            lo[2] = (short)f2bf(f0.z); lo[3] = (short)f2bf(f0.w);
            lo[4] = (short)f2bf(f1.x); lo[5] = (short)f2bf(f1.y);
            lo[6] = (short)f2bf(f1.z); lo[7] = (short)f2bf(f1.w);
            hi[0] = (short)f2bf(f2.x); hi[1] = (short)f2bf(f2.y);
            hi[2] = (short)f2bf(f2.z); hi[3] = (short)f2bf(f2.w);
            hi[4] = (short)f2bf(f3.x); hi[5] = (short)f2bf(f3.y);
            hi[6] = (short)f2bf(f3.z); hi[7] = (short)f2bf(f3.w);
            *(short8v*)&As[srow * 512 + ((sseg * 32 +  0) ^ ssw)] = lo;
            *(short8v*)&As[srow * 512 + ((sseg * 32 + 16) ^ ssw)] = hi;
        }
        __syncthreads();

        float4v accs[3];
        #pragma unroll
        for (int ct = 0; ct < 3; ++ct) accs[ct] = (float4v){0.f, 0.f, 0.f, 0.f};

        #pragma unroll
        for (int ks = 0; ks < 8; ++ks) {
            short8v a = *(const short8v*)&As[arow * 512 + ((ks * 64 + akb) ^ asw)];
            accs[0] = __builtin_amdgcn_mfma_f32_16x16x32_bf16(a, Bfr[0][ks], accs[0], 0, 0, 0);
            accs[1] = __builtin_amdgcn_mfma_f32_16x16x32_bf16(a, Bfr[1][ks], accs[1], 0, 0, 0);
            accs[2] = __builtin_amdgcn_mfma_f32_16x16x32_bf16(a, Bfr[2][ks], accs[2], 0, 0, 0);
        }

        #pragma unroll
        for (int ct = 0; ct < 3; ++ct) {
            const int gcol = w * 48 + ct * 16 + ccol;
            #pragma unroll
            for (int r = 0; r < 4; ++r) {
                const int row = n0 + crow0 + r;
                float v = accs[ct][r];
                if (gcol < 32) {
                    psh[(size_t)row * ED + gcol] = (_Float16)v;
                } else if (gcol < 64) {
                    pdh[(size_t)row * ED + (gcol - 32)] = (_Float16)v;
                } else {
                    float b = bc[gcol - 64];
                    hh[(size_t)row * H + (gcol - 64)] = (_Float16)fmaxf(v + b, 0.f);
                }
            }
        }
        __syncthreads();
    }
}

// ---------------- Kernel B: edge gate + deg (f16 gathers, 64 B/row) ----------------
__global__ __launch_bounds__(256) void edge_gate_kernel(
    const int* __restrict__ ei, const _Float16* __restrict__ psh,
    const _Float16* __restrict__ pdh, const float* __restrict__ be,
    const float* __restrict__ we2, const float* __restrict__ be2,
    float* __restrict__ gate, float* __restrict__ deg, int E)
{
    __shared__ float sbe[ED], swe2[ED];
    const int t = threadIdx.x;
    if (t < ED) { sbe[t] = be[t]; swe2[t] = we2[t]; }
    __syncthreads();

    const int e = blockIdx.x * 256 + t;
    if (e >= E) return;
    const int s = ei[e];
    const int d = ei[E + e];

    const half8v* p4 = (const half8v*)(psh + (size_t)s * ED);
    const half8v* q4 = (const half8v*)(pdh + (size_t)d * ED);
    float acc = 0.f;
    #pragma unroll
    for (int v = 0; v < 4; ++v) {
        half8v a = p4[v];
        half8v b = q4[v];
        #pragma unroll
        for (int j = 0; j < 8; ++j) {
            int k = v * 8 + j;
            float tt = (float)a[j] + (float)b[j] + sbe[k];
            acc += fmaxf(tt, 0.f) * swe2[k];
        }
    }
    float logit = acc + be2[0];
    float sg = 1.0f / (1.0f + expf(-logit));
    float gt = sg * 1.2f - 0.1f;
    gt = fminf(fmaxf(gt, 0.0f), 1.0f);
    gate[e] = gt;
    if (gt > 0.0f) atomicAdd(&deg[d], gt);
}

// ---------------- Kernel C: softmax stats over deg (single block) ----------------
__global__ __launch_bounds__(1024) void deg_stats_kernel(
    const float* __restrict__ deg, float* __restrict__ mS, int N)
{
    __shared__ float red[1024];
    const int t = threadIdx.x;
    float m = -1e30f;
    for (int i = t; i < N; i += 1024) m = fmaxf(m, deg[i]);
    red[t] = m; __syncthreads();
    for (int s = 512; s > 0; s >>= 1) {
        if (t < s) red[t] = fmaxf(red[t], red[t + s]);
        __syncthreads();
    }
    const float mx = red[0];
    __syncthreads();
    float sum = 0.f;
    for (int i = t; i < N; i += 1024) sum += expf(deg[i] - mx);
    red[t] = sum; __syncthreads();
    for (int s = 512; s > 0; s >>= 1) {
        if (t < s) red[t] += red[t + s];
        __syncthreads();
    }
    if (t == 0) { mS[0] = mx; mS[1] = red[0]; }
}

// ---------------- Kernel D: att + c elementwise ----------------
__global__ __launch_bounds__(256) void attc_kernel(
    const float* __restrict__ deg, const float* __restrict__ mS,
    float* __restrict__ att, float* __restrict__ c, int N)
{
    const int i = blockIdx.x * 256 + threadIdx.x;
    if (i >= N) return;
    float a = expf(deg[i] - mS[0]) / mS[1];
    att[i] = a;
    c[i] = a / (deg[i] + 1e-6f);
}

// ---------------- Kernel E: u[src] += gate*c[dst] ----------------
__global__ __launch_bounds__(256) void edge_u_kernel(
    const int* __restrict__ ei, const float* __restrict__ gate,
    const float* __restrict__ c, float* __restrict__ u, int E)
{
    const int e = blockIdx.x * 256 + threadIdx.x;
    if (e >= E) return;
    float gt = gate[e];
    if (gt != 0.f) {
        int s = ei[e];
        int d = ei[E + e];
        atomicAdd(&u[s], gt * c[d]);
    }
}

// ---------------- Kernel F: g = sum_i (att[i]+u[i]) * h[i,:] ----------------
__global__ __launch_bounds__(128) void pool_kernel(
    const _Float16* __restrict__ hh, const float* __restrict__ att,
    const float* __restrict__ u, float* __restrict__ gacc, int N)
{
    const int t = threadIdx.x;
    float acc = 0.f;
    for (int n = blockIdx.x; n < N; n += gridDim.x) {
        float wgt = att[n] + u[n];
        acc += wgt * (float)hh[(size_t)n * H + t];
    }
    atomicAdd(&gacc[t], acc);
}

// ---------------- Kernel G: classifier (1 wave) ----------------
__global__ __launch_bounds__(64) void cls_kernel(
    const float* __restrict__ gacc, const float* __restrict__ w1,
    const float* __restrict__ b1, const float* __restrict__ ln_g,
    const float* __restrict__ ln_b, const float* __restrict__ w2,
    const float* __restrict__ b2, float* __restrict__ out)
{
    __shared__ float gs[H];
    const int t = threadIdx.x;   // 0..63
    gs[t] = gacc[t];
    gs[t + 64] = gacc[t + 64];
    __syncthreads();

    float acc = b1[t];
    #pragma unroll 4
    for (int k = 0; k < H; ++k) acc += gs[k] * w1[k * 64 + t];
    float z = fmaxf(acc, 0.f);

    float sm = z;
    #pragma unroll
    for (int m = 1; m < 64; m <<= 1) sm += __shfl_xor(sm, m);
    float mn = sm * (1.0f / 64.0f);
    float dv = (z - mn) * (z - mn);
    float sv = dv;
    #pragma unroll
    for (int m = 1; m < 64; m <<= 1) sv += __shfl_xor(sv, m);
    float var = sv * (1.0f / 64.0f);

    float zn = (z - mn) * rsqrtf(var + 1e-5f) * ln_g[t] + ln_b[t];

    float w20 = w2[t * 2 + 0];
    float w21 = w2[t * 2 + 1];
    float ga = w20 * w20, gb = w20 * w21, gc = w21 * w21;
    float p0 = zn * w20, p1 = zn * w21;
    #pragma unroll
    for (int m = 1; m < 64; m <<= 1) {
        ga += __shfl_xor(ga, m);
        gb += __shfl_xor(gb, m);
        gc += __shfl_xor(gc, m);
        p0 += __shfl_xor(p0, m);
        p1 += __shfl_xor(p1, m);
    }
    if (t == 0) {
        float tr = ga + gc;
        float df = ga - gc;
        float eig = 0.5f * (tr + sqrtf(df * df + 4.0f * gb * gb));
        float sigma = sqrtf(eig);
        out[0] = p0 / sigma + b2[0];
        out[1] = p1 / sigma + b2[1];
    }
}

extern "C" void kernel_launch(void* const* d_in, const int* in_sizes, int n_in,
                              void* d_out, int out_size, void* d_ws, size_t ws_size,
                              hipStream_t stream) {
    const float* x      = (const float*)d_in[0];
    const int*   ei     = (const int*)  d_in[1];
    const float* we_src = (const float*)d_in[2];
    const float* we_dst = (const float*)d_in[3];
    const float* be     = (const float*)d_in[4];
    const float* we2    = (const float*)d_in[5];
    const float* be2    = (const float*)d_in[6];
    const float* wc     = (const float*)d_in[7];
    const float* bc     = (const float*)d_in[8];
    const float* w1     = (const float*)d_in[9];
    const float* b1     = (const float*)d_in[10];
    const float* ln_g   = (const float*)d_in[11];
    const float* ln_b   = (const float*)d_in[12];
    const float* w2     = (const float*)d_in[13];
    const float* b2     = (const float*)d_in[14];

    const int N = in_sizes[0] / F;
    const int E = in_sizes[1] / 2;
    const int M16 = N / 16;

    float* ws = (float*)d_ws;
    size_t off = 0;
    float* deg  = ws + off; off += (size_t)N;
    float* u    = ws + off; off += (size_t)N;
    float* gacc = ws + off; off += 128;
    const size_t zcount = off;             // deg, u, gacc zeroed together
    float* att  = ws + off; off += (size_t)N;
    float* c    = ws + off; off += (size_t)N;
    float* mS   = ws + off; off += 2;
    off = (off + 15) & ~(size_t)15;        // 64-B align
    unsigned short* Wp = (unsigned short*)(ws + off); off += (12 * 8 * 64 * 8) / 2;
    off = (off + 15) & ~(size_t)15;
    _Float16* psh = (_Float16*)(ws + off); off += (size_t)N * ED / 2;
    _Float16* pdh = (_Float16*)(ws + off); off += (size_t)N * ED / 2;
    _Float16* hh  = (_Float16*)(ws + off); off += (size_t)N * H / 2;
    float* gate = ws + off; off += (size_t)E;

    hipMemsetAsync(deg, 0, zcount * sizeof(float), stream);

    pack_kernel<<<(12 * 8 * 64 + 255) / 256, 256, 0, stream>>>(we_src, we_dst, wc, Wp);
    gemm_kernel<<<1024, 256, 0, stream>>>(x, Wp, bc, psh, pdh, hh, M16);
    edge_gate_kernel<<<(E + 255) / 256, 256, 0, stream>>>(ei, psh, pdh, be, we2, be2, gate, deg, E);
    deg_stats_kernel<<<1, 1024, 0, stream>>>(deg, mS, N);
    attc_kernel<<<(N + 255) / 256, 256, 0, stream>>>(deg, mS, att, c, N);
    edge_u_kernel<<<(E + 255) / 256, 256, 0, stream>>>(ei, gate, c, u, E);
    pool_kernel<<<512, 128, 0, stream>>>(hh, att, u, gacc, N);
    cls_kernel<<<1, 64, 0, stream>>>(gacc, w1, b1, ln_g, ln_b, w2, b2, (float*)d_out);
}